// Round 8
// baseline (224.628 us; speedup 1.0000x reference)
//
#include <hip/hip_runtime.h>
#include <hip/hip_bf16.h>

typedef unsigned int  uint;
typedef unsigned short ushort;
typedef short bf16x8 __attribute__((ext_vector_type(8)));
typedef float f32x4  __attribute__((ext_vector_type(4)));

#define HW   4096
#define KD   2304   // 9 taps * 256 c

__device__ __forceinline__ void load_lds16(const void* g, void* l) {
    __builtin_amdgcn_global_load_lds((const __attribute__((address_space(1))) void*)g,
                                     (__attribute__((address_space(3))) void*)l, 16, 0, 0);
}
__device__ __forceinline__ float blo(uint u) { return __uint_as_float(u << 16); }
__device__ __forceinline__ float bhi(uint u) { return __uint_as_float(u & 0xffff0000u); }
__device__ __forceinline__ uint pack2(float e, float o) {
    __hip_bfloat16 he = __float2bfloat16(e), ho = __float2bfloat16(o);
    return (uint)(*(ushort*)&he) | ((uint)(*(ushort*)&ho) << 16);
}

// ---- x -> bf16 position-major: x2t[(b*4096 + a)*128 + cp] = {c=2cp, c=2cp+1}
__global__ void prep_x2t(const float* __restrict__ x, uint* __restrict__ x2t) {
    __shared__ uint tl[32][65];
    int bidx = blockIdx.x;              // 4 b * 4 cpb * 64 ab = 1024
    int ab  = bidx & 63;
    int cpb = (bidx >> 6) & 3;
    int b   = bidx >> 8;
    int t = threadIdx.x;                // 256
#pragma unroll
    for (int i = 0; i < 8; ++i) {
        int idx = i * 256 + t;
        int cp = idx >> 6, a = idx & 63;           // cp in [0,32)
        const float* p = x + ((size_t)(b * 256 + (cpb * 32 + cp) * 2)) * HW + ab * 64 + a;
        tl[cp][a] = pack2(p[0], p[HW]);
    }
    __syncthreads();
#pragma unroll
    for (int i = 0; i < 8; ++i) {
        int idx = i * 256 + t;
        int a = idx >> 5, cp = idx & 31;
        x2t[((size_t)b * 4096 + ab * 64 + a) * 128 + cpb * 32 + cp] = tl[cp][a];
    }
}

// ---- w_def -> Bt[o*2304 + tap*256 + c]
__global__ void prep_bt(const float* __restrict__ w_def, ushort* __restrict__ bt) {
    int idx = blockIdx.x * 256 + threadIdx.x;      // 589,824
    int c   = idx & 255;
    int tap = (idx >> 8) % 9;
    int o   = idx / KD;
    __hip_bfloat16 h = __float2bfloat16(w_def[(o * 256 + c) * 9 + tap]);
    bt[idx] = *(ushort*)&h;
}

// ---- w_off -> Bt0[j*2304 + tap*256 + c], rows 18..31 zero
__global__ void prep_bt0(const float* __restrict__ w_off, ushort* __restrict__ bt0) {
    int idx = blockIdx.x * 256 + threadIdx.x;      // 73,728
    int c   = idx & 255;
    int tap = (idx >> 8) % 9;
    int j   = idx / KD;
    float v = (j < 18) ? w_off[(j * 256 + c) * 9 + tap] : 0.f;
    __hip_bfloat16 h = __float2bfloat16(v);
    bt0[idx] = *(ushort*)&h;
}

// ---- fused offset conv: direct implicit GEMM from x2t ----
__global__ __launch_bounds__(512) void gemm_off(const uint* __restrict__ x2t,
                                                const ushort* __restrict__ bt0,
                                                const float* __restrict__ b_off,
                                                float* __restrict__ off) {
    int id = blockIdx.x;
    int xcd = id & 7;
    int b = xcd >> 1, h = (xcd & 1) * 32 + (id >> 3);
    int t = threadIdx.x, wv = t >> 6, lane = t & 63;
    int mrow = lane & 15, quad = lane >> 4;
    int mq = wv & 3, nn = wv >> 2;

    __shared__ uint   lX[3 * 64 * 32];     // [dy][w][cp'] dwords, 24 KB
    __shared__ ushort lB[32 * 576];        // [o][72 chunks of 8, XOR-swizzled], 36 KB

    f32x4 acc = {0.f, 0.f, 0.f, 0.f};

    for (int cb = 0; cb < 4; ++cb) {
#pragma unroll
        for (int s = 0; s < 3; ++s) {      // 24 lX phases over 8 waves
            int q   = s * 8 + wv;
            int dy  = q >> 3;              // wave-uniform
            int y   = h + dy - 1;
            int sub = q & 7;
            int wl  = sub * 8 + (lane >> 3);
            int cps = ((lane & 7) ^ ((lane >> 3) & 7)) * 4;   // pre-swizzled source cp
            if ((unsigned)y < 64u) {
                const uint* src = x2t + ((size_t)(b * 4096 + y * 64 + wl)) * 128 + cb * 32 + cps;
                load_lds16(src, &lX[q * 256]);
            } else {
                uint4 z = {0u, 0u, 0u, 0u};
                *(uint4*)&lX[q * 256 + lane * 4] = z;
            }
        }
#pragma unroll
        for (int s = 0; s < 5; ++s) {      // 36 lB phases over 8 waves (guarded, wave-uniform)
            int q = s * 8 + wv;
            if (q < 36) {
                int e = q * 512 + lane * 8;
                int o  = e / 576;
                int r  = e - o * 576;
                int chp = r >> 3;
                int ch  = chp ^ (o & 7);
                int tap = ch >> 3, k8 = ch & 7;
                const ushort* src = bt0 + (size_t)o * KD + tap * 256 + cb * 64 + k8 * 8;
                load_lds16(src, &lB[q * 512]);
            }
        }
        __syncthreads();

#pragma unroll
        for (int tap = 0; tap < 9; ++tap) {
            int dy = tap / 3, dx = tap % 3;
            int xx = mq * 16 + mrow + dx - 1;
            bool vx = (unsigned)xx < 64u;
            int xc = min(max(xx, 0), 63);
#pragma unroll
            for (int kb = 0; kb < 2; ++kb) {
                int cp0 = kb * 16 + quad * 4;
                uint4 ad = {0u, 0u, 0u, 0u};
                if (vx) ad = *(const uint4*)&lX[dy * 2048 + xc * 32 + (cp0 ^ ((xc & 7) * 4))];
                bf16x8 af = *(bf16x8*)&ad;
                int o = nn * 16 + mrow;
                int chs = (tap * 8 + (((kb * 4 + quad)) ^ (o & 7)));
                bf16x8 bfr = *(const bf16x8*)&lB[o * 576 + chs * 8];
                acc = __builtin_amdgcn_mfma_f32_16x16x32_bf16(af, bfr, acc, 0, 0, 0);
            }
        }
        __syncthreads();
    }
    {
        int o = nn * 16 + mrow;
        float bias = (o < 18) ? b_off[o] : 0.f;
        f32x4 v = acc;
        v.x += bias; v.y += bias; v.z += bias; v.w += bias;
        int wpos = mq * 16 + quad * 4;
        *(f32x4*)(off + ((size_t)(b * 32 + o)) * HW + h * 64 + wpos) = v;
    }
}

// ---- fused gather + main GEMM + BN-stats ----
// P/C split, raw barriers, no-spill structure proven in R7 (56 µs).
// This round's single change: RESTORE the gather double-buffer (gA/gB) so
// gathers for slice s+2 are issued one full barrier-interval before finish
// consumes them — the ~600 cy VMEM latency that R7 exposed per slice moves
// off the critical path. waves_per_eu(4,4) gives the allocator a 128-VGPR
// budget for the +16 live regs (watch VGPR_Count / WRITE_SIZE for spill).
__global__ __attribute__((amdgpu_waves_per_eu(4, 4))) __launch_bounds__(1024)
void fused_main(const uint* __restrict__ x2t,
                const ushort* __restrict__ bt,
                const float* __restrict__ off,
                float* __restrict__ out,
                float* __restrict__ stats) {
    int id = blockIdx.x;                      // 256 blocks
    int xcd = id & 7;
    int b = xcd >> 1, h = (xcd & 1) * 32 + (id >> 3);
    int t = threadIdx.x;
    int wv = t >> 6, lane = t & 63;
    int mrow = lane & 15, quad = lane >> 4;
    bool producer = (wv < 8);
    int ppos = (wv << 3) + (lane >> 3);       // producer position 0..63
    int pc8  = lane & 7;                      // producer 16B chunk (4 cp)
    int wvc  = wv - 8;                        // consumer wave 0..7

    __shared__ int    sAc[4][9][64];          // corner plane offsets, 9 KB
    __shared__ float  sWc[4][9][64];          // corner weights, 9 KB
    __shared__ ushort lA[2][64 * 64];         // 2 x 8 KB

    // ---- per-tile coords for all 9 taps ----
    for (int i = t; i < 576; i += 1024) {
        int tap = i >> 6, ww = i & 63;
        int hw = h * 64 + ww;
        float oy = off[((size_t)(b * 32 + 2 * tap)) * HW + hw];
        float ox = off[((size_t)(b * 32 + 2 * tap + 1)) * HW + hw];
        float py = oy + (float)(tap / 3 + h - 1);
        float px = ox + (float)(tap % 3 + ww - 1);
        float y0f = floorf(py), x0f = floorf(px);
        float wy1 = py - y0f, wx1 = px - x0f;
        float wy0 = 1.f - wy1, wx0 = 1.f - wx1;
        bool vy0 = (y0f >= 0.f) && (y0f <= 63.f);
        bool vy1 = (y0f >= -1.f) && (y0f <= 62.f);
        bool vx0 = (x0f >= 0.f) && (x0f <= 63.f);
        bool vx1 = (x0f >= -1.f) && (x0f <= 62.f);
        int iy0 = min(max((int)y0f, 0), 63),  iy1 = min(max((int)y0f + 1, 0), 63);
        int ix0 = min(max((int)x0f, 0), 63),  ix1 = min(max((int)x0f + 1, 0), 63);
        sAc[0][tap][ww] = iy0 * 64 + ix0;
        sAc[1][tap][ww] = iy0 * 64 + ix1;
        sAc[2][tap][ww] = iy1 * 64 + ix0;
        sAc[3][tap][ww] = iy1 * 64 + ix1;
        sWc[0][tap][ww] = wy0 * wx0 * (float)(vy0 && vx0);
        sWc[1][tap][ww] = wy0 * wx1 * (float)(vy0 && vx1);
        sWc[2][tap][ww] = wy1 * wx0 * (float)(vy1 && vx0);
        sWc[3][tap][ww] = wy1 * wx1 * (float)(vy1 && vx1);
    }
    __syncthreads();

    f32x4 acc[4][2];
#pragma unroll
    for (int m = 0; m < 4; ++m)
#pragma unroll
        for (int n = 0; n < 2; ++n) acc[m][n] = {0.f, 0.f, 0.f, 0.f};

    const uint* xb = x2t + (size_t)b * 4096 * 128;

    // producer: issue the 4 corner gathers for slice sl into reg set g (no wait)
    auto issue_gathers = [&](int sl, uint4 (&g)[4]) {
        int tap = sl >> 2, cb = sl & 3;
        const uint* xp = xb + cb * 32 + pc8 * 4;
        g[0] = *(const uint4*)(xp + (size_t)sAc[0][tap][ppos] * 128);
        g[1] = *(const uint4*)(xp + (size_t)sAc[1][tap][ppos] * 128);
        g[2] = *(const uint4*)(xp + (size_t)sAc[2][tap][ppos] * 128);
        g[3] = *(const uint4*)(xp + (size_t)sAc[3][tap][ppos] * 128);
    };
    // producer: interp + pack + LDS write for slice sl from reg set g
    auto finish = [&](int sl, ushort* lAb, const uint4 (&g)[4]) {
        int tap = sl >> 2;
        float f0 = sWc[0][tap][ppos], f1 = sWc[1][tap][ppos];
        float f2 = sWc[2][tap][ppos], f3 = sWc[3][tap][ppos];
        const uint* c0 = (const uint*)&g[0];
        const uint* c1 = (const uint*)&g[1];
        const uint* c2 = (const uint*)&g[2];
        const uint* c3 = (const uint*)&g[3];
        uint r[4];
#pragma unroll
        for (int j = 0; j < 4; ++j) {
            float ev = f0 * blo(c0[j]) + f1 * blo(c1[j]) + f2 * blo(c2[j]) + f3 * blo(c3[j]);
            float ov = f0 * bhi(c0[j]) + f1 * bhi(c1[j]) + f2 * bhi(c2[j]) + f3 * bhi(c3[j]);
            r[j] = pack2(ev, ov);
        }
        uint4 gg = {r[0], r[1], r[2], r[3]};
        *(uint4*)&lAb[ppos * 64 + ((pc8 ^ (ppos & 7)) * 8)] = gg;
    };
    // consumer: load this wave's B fragments for slice sl from global into regs
    auto loadB = [&](int sl, bf16x8 (&br)[4]) {
        int tap = sl >> 2, cb = sl & 3;
        const ushort* base = bt + tap * 256 + cb * 64 + quad * 8;
#pragma unroll
        for (int kb = 0; kb < 2; ++kb)
#pragma unroll
            for (int n = 0; n < 2; ++n) {
                int r = wvc * 32 + n * 16 + mrow;
                br[kb * 2 + n] = *(const bf16x8*)(base + (size_t)r * KD + kb * 32);
            }
    };
    // consumer: MFMA pass over lA buffer bi with B fragments br
    auto mfma_pass = [&](int bi, const bf16x8 (&br)[4]) {
#pragma unroll
        for (int kb = 0; kb < 2; ++kb) {
            bf16x8 af[4];
#pragma unroll
            for (int m = 0; m < 4; ++m) {
                int r = m * 16 + mrow;
                af[m] = *(const bf16x8*)&lA[bi][r * 64 + (((kb * 4 + quad) ^ (r & 7)) * 8)];
            }
#pragma unroll
            for (int n = 0; n < 2; ++n)
#pragma unroll
                for (int m = 0; m < 4; ++m)
                    acc[m][n] = __builtin_amdgcn_mfma_f32_16x16x32_bf16(af[m], br[kb * 2 + n], acc[m][n], 0, 0, 0);
        }
    };

    uint4 gA[4], gB[4];
    bf16x8 brA[4], brB[4];
    // ---- prologue ----
    if (producer) {
        issue_gathers(0, gA);
        finish(0, lA[0], gA);          // compiler waits on gathers(0) by dep
        issue_gathers(1, gB);          // in flight across the barrier
        asm volatile("s_waitcnt lgkmcnt(0)" ::: "memory");   // publish lA[0]
    } else {
        loadB(0, brA);
        loadB(1, brB);
    }
    __builtin_amdgcn_s_barrier();              // lA[0] ready
    __builtin_amdgcn_sched_barrier(0);

    // slice s in lA[s&1]; raw barriers keep gather+B prefetch in flight across.
    for (int s = 0; s < 36; s += 2) {
        // interval A: consume slice s (lA[0], brA); produce slice s+1 -> lA[1]
        if (producer) {
            if (s + 2 < 36) issue_gathers(s + 2, gA);
            finish(s + 1, lA[1], gB);  // gB issued one interval ago: latency hidden
            asm volatile("s_waitcnt lgkmcnt(0)" ::: "memory");   // publish lA[1]
        } else {
            __builtin_amdgcn_s_setprio(1);
            mfma_pass(0, brA);
            __builtin_amdgcn_s_setprio(0);
            if (s + 2 < 36) loadB(s + 2, brA);   // lands 2 barriers later
        }
        __builtin_amdgcn_s_barrier();          // lA[1] ready; lA[0] free
        __builtin_amdgcn_sched_barrier(0);
        // interval B: consume slice s+1 (lA[1], brB); produce slice s+2 -> lA[0]
        if (producer) {
            if (s + 3 < 36) issue_gathers(s + 3, gB);
            if (s + 2 < 36) {
                finish(s + 2, lA[0], gA);
                asm volatile("s_waitcnt lgkmcnt(0)" ::: "memory");   // publish lA[0]
            }
        } else {
            __builtin_amdgcn_s_setprio(1);
            mfma_pass(1, brB);
            __builtin_amdgcn_s_setprio(0);
            if (s + 3 < 36) loadB(s + 3, brB);
        }
        __builtin_amdgcn_s_barrier();          // lA[0] ready; lA[1] free
        __builtin_amdgcn_sched_barrier(0);
    }

    // ---- epilogue (consumers only): store + BN stats ----
    if (!producer) {
#pragma unroll
        for (int n = 0; n < 2; ++n) {
            int o = wvc * 32 + n * 16 + mrow;
            float ss = 0.f, qq = 0.f;
#pragma unroll
            for (int m = 0; m < 4; ++m) {
                int pos = m * 16 + quad * 4;
                f32x4 v = acc[m][n];
                *(f32x4*)(out + ((size_t)(b * 256 + o)) * HW + h * 64 + pos) = v;
                ss += v.x + v.y + v.z + v.w;
                qq += v.x * v.x + v.y * v.y + v.z * v.z + v.w * v.w;
            }
            ss += __shfl_xor(ss, 16); ss += __shfl_xor(ss, 32);
            qq += __shfl_xor(qq, 16); qq += __shfl_xor(qq, 32);
            if (quad == 0) {
                atomicAdd(&stats[o], ss);
                atomicAdd(&stats[512 + o], qq);
            }
        }
    }
}

// ---- BN finalize + apply ----
__global__ void bn_finalize(const float* __restrict__ stats,
                            const float* __restrict__ gamma,
                            float* __restrict__ ms) {
    int o = threadIdx.x;                      // 256
    float S = stats[o], S2 = stats[512 + o];
    float m  = S / 16384.f;
    float var = S2 / 16384.f - m * m;
    ms[o]       = m;
    ms[256 + o] = gamma[o] * rsqrtf(var + 1e-5f);
}

__global__ void bn_apply(float* __restrict__ out,
                         const float* __restrict__ ms,
                         const float* __restrict__ beta) {
    int idx4 = blockIdx.x * 256 + threadIdx.x;   // 1,048,576 float4s
    int o = (idx4 >> 10) & 255;
    float4 v = ((const float4*)out)[idx4];
    float mu = ms[o], sc = ms[256 + o], be = beta[o];
    v.x = fmaxf((v.x - mu) * sc + be, 0.f);
    v.y = fmaxf((v.y - mu) * sc + be, 0.f);
    v.z = fmaxf((v.z - mu) * sc + be, 0.f);
    v.w = fmaxf((v.w - mu) * sc + be, 0.f);
    ((float4*)out)[idx4] = v;
}

extern "C" void kernel_launch(void* const* d_in, const int* in_sizes, int n_in,
                              void* d_out, int out_size, void* d_ws, size_t ws_size,
                              hipStream_t stream) {
    const float* x     = (const float*)d_in[0];
    const float* w_off = (const float*)d_in[1];
    const float* b_off = (const float*)d_in[2];
    const float* w_def = (const float*)d_in[3];
    const float* gamma = (const float*)d_in[4];
    const float* beta  = (const float*)d_in[5];
    float* out = (float*)d_out;

    char* ws = (char*)d_ws;
    uint*   x2t   = (uint*)ws;                          // 8,388,608 B
    ushort* bt    = (ushort*)(ws + 8388608);            // 1,179,648 B
    ushort* bt0   = (ushort*)(ws + 9568256);            // 147,456 B
    float*  off   = (float*)(ws + 9715712);             // 2,097,152 B
    float*  stats = (float*)(ws + 11812864);            // 4,096 B
    float*  ms    = (float*)(ws + 11816960);            // 2,048 B

    hipMemsetAsync(stats, 0, 4096, stream);
    prep_x2t<<<1024, 256, 0, stream>>>(x, x2t);
    prep_bt <<<2304, 256, 0, stream>>>(w_def, bt);
    prep_bt0<<<288,  256, 0, stream>>>(w_off, bt0);
    gemm_off<<<256, 512, 0, stream>>>(x2t, bt0, b_off, off);
    fused_main<<<256, 1024, 0, stream>>>(x2t, bt, off, out, stats);
    bn_finalize<<<1, 256, 0, stream>>>(stats, gamma, ms);
    bn_apply<<<4096, 256, 0, stream>>>(out, ms, beta);
}

// Round 9
// 154.893 us; speedup vs baseline: 1.4502x; 1.4502x over previous
//
#include <hip/hip_runtime.h>
#include <hip/hip_bf16.h>

typedef unsigned int  uint;
typedef unsigned short ushort;
typedef short bf16x8 __attribute__((ext_vector_type(8)));
typedef float f32x4  __attribute__((ext_vector_type(4)));

#define HW   4096
#define KD   2304   // 9 taps * 256 c

__device__ __forceinline__ void load_lds16(const void* g, void* l) {
    __builtin_amdgcn_global_load_lds((const __attribute__((address_space(1))) void*)g,
                                     (__attribute__((address_space(3))) void*)l, 16, 0, 0);
}
__device__ __forceinline__ float blo(uint u) { return __uint_as_float(u << 16); }
__device__ __forceinline__ float bhi(uint u) { return __uint_as_float(u & 0xffff0000u); }
__device__ __forceinline__ uint pack2(float e, float o) {
    __hip_bfloat16 he = __float2bfloat16(e), ho = __float2bfloat16(o);
    return (uint)(*(ushort*)&he) | ((uint)(*(ushort*)&ho) << 16);
}

// ---- x -> bf16 position-major: x2t[(b*4096 + a)*128 + cp] = {c=2cp, c=2cp+1}
__global__ void prep_x2t(const float* __restrict__ x, uint* __restrict__ x2t) {
    __shared__ uint tl[32][65];
    int bidx = blockIdx.x;              // 4 b * 4 cpb * 64 ab = 1024
    int ab  = bidx & 63;
    int cpb = (bidx >> 6) & 3;
    int b   = bidx >> 8;
    int t = threadIdx.x;                // 256
#pragma unroll
    for (int i = 0; i < 8; ++i) {
        int idx = i * 256 + t;
        int cp = idx >> 6, a = idx & 63;           // cp in [0,32)
        const float* p = x + ((size_t)(b * 256 + (cpb * 32 + cp) * 2)) * HW + ab * 64 + a;
        tl[cp][a] = pack2(p[0], p[HW]);
    }
    __syncthreads();
#pragma unroll
    for (int i = 0; i < 8; ++i) {
        int idx = i * 256 + t;
        int a = idx >> 5, cp = idx & 31;
        x2t[((size_t)b * 4096 + ab * 64 + a) * 128 + cpb * 32 + cp] = tl[cp][a];
    }
}

// ---- w_def -> Bt[o*2304 + tap*256 + c]
__global__ void prep_bt(const float* __restrict__ w_def, ushort* __restrict__ bt) {
    int idx = blockIdx.x * 256 + threadIdx.x;      // 589,824
    int c   = idx & 255;
    int tap = (idx >> 8) % 9;
    int o   = idx / KD;
    __hip_bfloat16 h = __float2bfloat16(w_def[(o * 256 + c) * 9 + tap]);
    bt[idx] = *(ushort*)&h;
}

// ---- w_off -> Bt0[j*2304 + tap*256 + c], rows 18..31 zero
__global__ void prep_bt0(const float* __restrict__ w_off, ushort* __restrict__ bt0) {
    int idx = blockIdx.x * 256 + threadIdx.x;      // 73,728
    int c   = idx & 255;
    int tap = (idx >> 8) % 9;
    int j   = idx / KD;
    float v = (j < 18) ? w_off[(j * 256 + c) * 9 + tap] : 0.f;
    __hip_bfloat16 h = __float2bfloat16(v);
    bt0[idx] = *(ushort*)&h;
}

// ---- fused offset conv: direct implicit GEMM from x2t ----
__global__ __launch_bounds__(512) void gemm_off(const uint* __restrict__ x2t,
                                                const ushort* __restrict__ bt0,
                                                const float* __restrict__ b_off,
                                                float* __restrict__ off) {
    int id = blockIdx.x;
    int xcd = id & 7;
    int b = xcd >> 1, h = (xcd & 1) * 32 + (id >> 3);
    int t = threadIdx.x, wv = t >> 6, lane = t & 63;
    int mrow = lane & 15, quad = lane >> 4;
    int mq = wv & 3, nn = wv >> 2;

    __shared__ uint   lX[3 * 64 * 32];     // [dy][w][cp'] dwords, 24 KB
    __shared__ ushort lB[32 * 576];        // [o][72 chunks of 8, XOR-swizzled], 36 KB

    f32x4 acc = {0.f, 0.f, 0.f, 0.f};

    for (int cb = 0; cb < 4; ++cb) {
#pragma unroll
        for (int s = 0; s < 3; ++s) {      // 24 lX phases over 8 waves
            int q   = s * 8 + wv;
            int dy  = q >> 3;              // wave-uniform
            int y   = h + dy - 1;
            int sub = q & 7;
            int wl  = sub * 8 + (lane >> 3);
            int cps = ((lane & 7) ^ ((lane >> 3) & 7)) * 4;   // pre-swizzled source cp
            if ((unsigned)y < 64u) {
                const uint* src = x2t + ((size_t)(b * 4096 + y * 64 + wl)) * 128 + cb * 32 + cps;
                load_lds16(src, &lX[q * 256]);
            } else {
                uint4 z = {0u, 0u, 0u, 0u};
                *(uint4*)&lX[q * 256 + lane * 4] = z;
            }
        }
#pragma unroll
        for (int s = 0; s < 5; ++s) {      // 36 lB phases over 8 waves (guarded, wave-uniform)
            int q = s * 8 + wv;
            if (q < 36) {
                int e = q * 512 + lane * 8;
                int o  = e / 576;
                int r  = e - o * 576;
                int chp = r >> 3;
                int ch  = chp ^ (o & 7);
                int tap = ch >> 3, k8 = ch & 7;
                const ushort* src = bt0 + (size_t)o * KD + tap * 256 + cb * 64 + k8 * 8;
                load_lds16(src, &lB[q * 512]);
            }
        }
        __syncthreads();

#pragma unroll
        for (int tap = 0; tap < 9; ++tap) {
            int dy = tap / 3, dx = tap % 3;
            int xx = mq * 16 + mrow + dx - 1;
            bool vx = (unsigned)xx < 64u;
            int xc = min(max(xx, 0), 63);
#pragma unroll
            for (int kb = 0; kb < 2; ++kb) {
                int cp0 = kb * 16 + quad * 4;
                uint4 ad = {0u, 0u, 0u, 0u};
                if (vx) ad = *(const uint4*)&lX[dy * 2048 + xc * 32 + (cp0 ^ ((xc & 7) * 4))];
                bf16x8 af = *(bf16x8*)&ad;
                int o = nn * 16 + mrow;
                int chs = (tap * 8 + (((kb * 4 + quad)) ^ (o & 7)));
                bf16x8 bfr = *(const bf16x8*)&lB[o * 576 + chs * 8];
                acc = __builtin_amdgcn_mfma_f32_16x16x32_bf16(af, bfr, acc, 0, 0, 0);
            }
        }
        __syncthreads();
    }
    {
        int o = nn * 16 + mrow;
        float bias = (o < 18) ? b_off[o] : 0.f;
        f32x4 v = acc;
        v.x += bias; v.y += bias; v.z += bias; v.w += bias;
        int wpos = mq * 16 + quad * 4;
        *(f32x4*)(off + ((size_t)(b * 32 + o)) * HW + h * 64 + wpos) = v;
    }
}

// ---- fused gather + main GEMM + BN-stats ----
// P/C split, raw barriers (R7 structure = 56 µs, no spill). R8 showed any
// extra reg buffer across a barrier spills (allocator pinned at 64 arch-VGPR).
// This round: gather double-buffer lives in LDS via global_load_lds with
// PER-LANE global source (zero VGPR cost). Producer: issue DMA for slice
// sl+1 -> cS[(sl+1)&1]; counted vmcnt(4) (newest 4 stay in flight, T4);
// ds_read own wave's corners of slice sl from cS[sl&1]; interp; lA write.
// cS is wave-private (same wave stages & reads) -> no barrier needed on it.
__global__ __attribute__((amdgpu_waves_per_eu(4, 4))) __launch_bounds__(1024)
void fused_main(const uint* __restrict__ x2t,
                const ushort* __restrict__ bt,
                const float* __restrict__ off,
                float* __restrict__ out,
                float* __restrict__ stats) {
    int id = blockIdx.x;                      // 256 blocks
    int xcd = id & 7;
    int b = xcd >> 1, h = (xcd & 1) * 32 + (id >> 3);
    int t = threadIdx.x;
    int wv = t >> 6, lane = t & 63;
    int mrow = lane & 15, quad = lane >> 4;
    bool producer = (wv < 8);
    int ppos = (wv << 3) + (lane >> 3);       // producer position 0..63
    int pc8  = lane & 7;                      // producer 16B chunk (4 cp)
    int wvc  = wv - 8;                        // consumer wave 0..7

    __shared__ int    sAc[4][9][64];          // corner plane offsets, 9 KB
    __shared__ float  sWc[4][9][64];          // corner weights, 9 KB
    __shared__ ushort lA[2][64 * 64];         // 2 x 8 KB
    __shared__ uint4  cS[2][4][512];          // corner staging, 2 x 32 KB (DMA dest)

    // ---- per-tile coords for all 9 taps ----
    for (int i = t; i < 576; i += 1024) {
        int tap = i >> 6, ww = i & 63;
        int hw = h * 64 + ww;
        float oy = off[((size_t)(b * 32 + 2 * tap)) * HW + hw];
        float ox = off[((size_t)(b * 32 + 2 * tap + 1)) * HW + hw];
        float py = oy + (float)(tap / 3 + h - 1);
        float px = ox + (float)(tap % 3 + ww - 1);
        float y0f = floorf(py), x0f = floorf(px);
        float wy1 = py - y0f, wx1 = px - x0f;
        float wy0 = 1.f - wy1, wx0 = 1.f - wx1;
        bool vy0 = (y0f >= 0.f) && (y0f <= 63.f);
        bool vy1 = (y0f >= -1.f) && (y0f <= 62.f);
        bool vx0 = (x0f >= 0.f) && (x0f <= 63.f);
        bool vx1 = (x0f >= -1.f) && (x0f <= 62.f);
        int iy0 = min(max((int)y0f, 0), 63),  iy1 = min(max((int)y0f + 1, 0), 63);
        int ix0 = min(max((int)x0f, 0), 63),  ix1 = min(max((int)x0f + 1, 0), 63);
        sAc[0][tap][ww] = iy0 * 64 + ix0;
        sAc[1][tap][ww] = iy0 * 64 + ix1;
        sAc[2][tap][ww] = iy1 * 64 + ix0;
        sAc[3][tap][ww] = iy1 * 64 + ix1;
        sWc[0][tap][ww] = wy0 * wx0 * (float)(vy0 && vx0);
        sWc[1][tap][ww] = wy0 * wx1 * (float)(vy0 && vx1);
        sWc[2][tap][ww] = wy1 * wx0 * (float)(vy1 && vx0);
        sWc[3][tap][ww] = wy1 * wx1 * (float)(vy1 && vx1);
    }
    __syncthreads();

    f32x4 acc[4][2];
#pragma unroll
    for (int m = 0; m < 4; ++m)
#pragma unroll
        for (int n = 0; n < 2; ++n) acc[m][n] = {0.f, 0.f, 0.f, 0.f};

    const uint* xb = x2t + (size_t)b * 4096 * 128;

    // producer: DMA the 4 corner gathers for slice sl into cS[sl&1] (no wait,
    // no VGPR). Per-lane global src, wave-uniform LDS base + lane*16 dest.
    auto issue_gathers = [&](int sl) {
        int par = sl & 1, tap = sl >> 2, cb = sl & 3;
        const uint* xp = xb + cb * 32 + pc8 * 4;
#pragma unroll
        for (int c = 0; c < 4; ++c) {
            const uint* src = xp + (size_t)sAc[c][tap][ppos] * 128;
            load_lds16(src, &cS[par][c][wv * 64]);
        }
    };
    // producer: read own wave's staged corners of slice sl, interp, write lA
    auto finish = [&](int sl, ushort* lAb) {
        int par = sl & 1, tap = sl >> 2;
        float f0 = sWc[0][tap][ppos], f1 = sWc[1][tap][ppos];
        float f2 = sWc[2][tap][ppos], f3 = sWc[3][tap][ppos];
        uint4 v0 = cS[par][0][wv * 64 + lane];
        uint4 v1 = cS[par][1][wv * 64 + lane];
        uint4 v2 = cS[par][2][wv * 64 + lane];
        uint4 v3 = cS[par][3][wv * 64 + lane];
        const uint* c0 = (const uint*)&v0;
        const uint* c1 = (const uint*)&v1;
        const uint* c2 = (const uint*)&v2;
        const uint* c3 = (const uint*)&v3;
        uint r[4];
#pragma unroll
        for (int j = 0; j < 4; ++j) {
            float ev = f0 * blo(c0[j]) + f1 * blo(c1[j]) + f2 * blo(c2[j]) + f3 * blo(c3[j]);
            float ov = f0 * bhi(c0[j]) + f1 * bhi(c1[j]) + f2 * bhi(c2[j]) + f3 * bhi(c3[j]);
            r[j] = pack2(ev, ov);
        }
        uint4 gg = {r[0], r[1], r[2], r[3]};
        *(uint4*)&lAb[ppos * 64 + ((pc8 ^ (ppos & 7)) * 8)] = gg;
    };
    // consumer: load this wave's B fragments for slice sl from global into regs
    auto loadB = [&](int sl, bf16x8 (&br)[4]) {
        int tap = sl >> 2, cb = sl & 3;
        const ushort* base = bt + tap * 256 + cb * 64 + quad * 8;
#pragma unroll
        for (int kb = 0; kb < 2; ++kb)
#pragma unroll
            for (int n = 0; n < 2; ++n) {
                int r = wvc * 32 + n * 16 + mrow;
                br[kb * 2 + n] = *(const bf16x8*)(base + (size_t)r * KD + kb * 32);
            }
    };
    // consumer: MFMA pass over lA buffer bi with B fragments br
    auto mfma_pass = [&](int bi, const bf16x8 (&br)[4]) {
#pragma unroll
        for (int kb = 0; kb < 2; ++kb) {
            bf16x8 af[4];
#pragma unroll
            for (int m = 0; m < 4; ++m) {
                int r = m * 16 + mrow;
                af[m] = *(const bf16x8*)&lA[bi][r * 64 + (((kb * 4 + quad) ^ (r & 7)) * 8)];
            }
#pragma unroll
            for (int n = 0; n < 2; ++n)
#pragma unroll
                for (int m = 0; m < 4; ++m)
                    acc[m][n] = __builtin_amdgcn_mfma_f32_16x16x32_bf16(af[m], br[kb * 2 + n], acc[m][n], 0, 0, 0);
        }
    };

    bf16x8 brA[4], brB[4];
    // ---- prologue: slices 0 and 1 DMA'd; finish slice 0 into lA[0] ----
    if (producer) {
        issue_gathers(0);                                  // 4 in flight
        issue_gathers(1);                                  // 8 in flight
        asm volatile("s_waitcnt vmcnt(4)" ::: "memory");   // slice 0 landed
        __builtin_amdgcn_sched_barrier(0);
        finish(0, lA[0]);
        asm volatile("s_waitcnt lgkmcnt(0)" ::: "memory"); // publish lA[0]
    } else {
        loadB(0, brA);
        loadB(1, brB);
    }
    __builtin_amdgcn_s_barrier();              // lA[0] ready
    __builtin_amdgcn_sched_barrier(0);

    // slice s in lA[s&1]; gather DMA + B prefetch stay in flight across barriers.
    for (int s = 0; s < 36; s += 2) {
        // interval A: consume slice s (lA[0], brA); produce slice s+1 -> lA[1]
        if (producer) {
            if (s + 2 < 36) {
                issue_gathers(s + 2);                              // -> cS[0]
                asm volatile("s_waitcnt vmcnt(4)" ::: "memory");   // s+1 landed
            } else {
                asm volatile("s_waitcnt vmcnt(0)" ::: "memory");
            }
            __builtin_amdgcn_sched_barrier(0);
            finish(s + 1, lA[1]);                                  // reads cS[1]
            asm volatile("s_waitcnt lgkmcnt(0)" ::: "memory");     // publish lA[1]
        } else {
            __builtin_amdgcn_s_setprio(1);
            mfma_pass(0, brA);
            __builtin_amdgcn_s_setprio(0);
            if (s + 2 < 36) loadB(s + 2, brA);   // lands 2 barriers later
        }
        __builtin_amdgcn_s_barrier();          // lA[1] ready; lA[0] free
        __builtin_amdgcn_sched_barrier(0);
        // interval B: consume slice s+1 (lA[1], brB); produce slice s+2 -> lA[0]
        if (producer) {
            if (s + 3 < 36) issue_gathers(s + 3);                  // -> cS[1]
            if (s + 2 < 36) {
                if (s + 3 < 36) {
                    asm volatile("s_waitcnt vmcnt(4)" ::: "memory");   // s+2 landed
                } else {
                    asm volatile("s_waitcnt vmcnt(0)" ::: "memory");
                }
                __builtin_amdgcn_sched_barrier(0);
                finish(s + 2, lA[0]);                              // reads cS[0]
                asm volatile("s_waitcnt lgkmcnt(0)" ::: "memory"); // publish lA[0]
            }
        } else {
            __builtin_amdgcn_s_setprio(1);
            mfma_pass(1, brB);
            __builtin_amdgcn_s_setprio(0);
            if (s + 3 < 36) loadB(s + 3, brB);
        }
        __builtin_amdgcn_s_barrier();          // lA[0] ready; lA[1] free
        __builtin_amdgcn_sched_barrier(0);
    }

    // ---- epilogue (consumers only): store + BN stats ----
    if (!producer) {
#pragma unroll
        for (int n = 0; n < 2; ++n) {
            int o = wvc * 32 + n * 16 + mrow;
            float ss = 0.f, qq = 0.f;
#pragma unroll
            for (int m = 0; m < 4; ++m) {
                int pos = m * 16 + quad * 4;
                f32x4 v = acc[m][n];
                *(f32x4*)(out + ((size_t)(b * 256 + o)) * HW + h * 64 + pos) = v;
                ss += v.x + v.y + v.z + v.w;
                qq += v.x * v.x + v.y * v.y + v.z * v.z + v.w * v.w;
            }
            ss += __shfl_xor(ss, 16); ss += __shfl_xor(ss, 32);
            qq += __shfl_xor(qq, 16); qq += __shfl_xor(qq, 32);
            if (quad == 0) {
                atomicAdd(&stats[o], ss);
                atomicAdd(&stats[512 + o], qq);
            }
        }
    }
}

// ---- BN finalize + apply ----
__global__ void bn_finalize(const float* __restrict__ stats,
                            const float* __restrict__ gamma,
                            float* __restrict__ ms) {
    int o = threadIdx.x;                      // 256
    float S = stats[o], S2 = stats[512 + o];
    float m  = S / 16384.f;
    float var = S2 / 16384.f - m * m;
    ms[o]       = m;
    ms[256 + o] = gamma[o] * rsqrtf(var + 1e-5f);
}

__global__ void bn_apply(float* __restrict__ out,
                         const float* __restrict__ ms,
                         const float* __restrict__ beta) {
    int idx4 = blockIdx.x * 256 + threadIdx.x;   // 1,048,576 float4s
    int o = (idx4 >> 10) & 255;
    float4 v = ((const float4*)out)[idx4];
    float mu = ms[o], sc = ms[256 + o], be = beta[o];
    v.x = fmaxf((v.x - mu) * sc + be, 0.f);
    v.y = fmaxf((v.y - mu) * sc + be, 0.f);
    v.z = fmaxf((v.z - mu) * sc + be, 0.f);
    v.w = fmaxf((v.w - mu) * sc + be, 0.f);
    ((float4*)out)[idx4] = v;
}

extern "C" void kernel_launch(void* const* d_in, const int* in_sizes, int n_in,
                              void* d_out, int out_size, void* d_ws, size_t ws_size,
                              hipStream_t stream) {
    const float* x     = (const float*)d_in[0];
    const float* w_off = (const float*)d_in[1];
    const float* b_off = (const float*)d_in[2];
    const float* w_def = (const float*)d_in[3];
    const float* gamma = (const float*)d_in[4];
    const float* beta  = (const float*)d_in[5];
    float* out = (float*)d_out;

    char* ws = (char*)d_ws;
    uint*   x2t   = (uint*)ws;                          // 8,388,608 B
    ushort* bt    = (ushort*)(ws + 8388608);            // 1,179,648 B
    ushort* bt0   = (ushort*)(ws + 9568256);            // 147,456 B
    float*  off   = (float*)(ws + 9715712);             // 2,097,152 B
    float*  stats = (float*)(ws + 11812864);            // 4,096 B
    float*  ms    = (float*)(ws + 11816960);            // 2,048 B

    hipMemsetAsync(stats, 0, 4096, stream);
    prep_x2t<<<1024, 256, 0, stream>>>(x, x2t);
    prep_bt <<<2304, 256, 0, stream>>>(w_def, bt);
    prep_bt0<<<288,  256, 0, stream>>>(w_off, bt0);
    gemm_off<<<256, 512, 0, stream>>>(x2t, bt0, b_off, off);
    fused_main<<<256, 1024, 0, stream>>>(x2t, bt, off, out, stats);
    bn_finalize<<<1, 256, 0, stream>>>(stats, gamma, ms);
    bn_apply<<<4096, 256, 0, stream>>>(out, ms, beta);
}

// Round 10
// 148.641 us; speedup vs baseline: 1.5112x; 1.0421x over previous
//
#include <hip/hip_runtime.h>
#include <hip/hip_bf16.h>

typedef unsigned int  uint;
typedef unsigned short ushort;
typedef short bf16x8 __attribute__((ext_vector_type(8)));
typedef float f32x4  __attribute__((ext_vector_type(4)));

#define HW   4096
#define KD   2304   // 9 taps * 256 c

__device__ __forceinline__ void load_lds16(const void* g, void* l) {
    __builtin_amdgcn_global_load_lds((const __attribute__((address_space(1))) void*)g,
                                     (__attribute__((address_space(3))) void*)l, 16, 0, 0);
}
__device__ __forceinline__ float blo(uint u) { return __uint_as_float(u << 16); }
__device__ __forceinline__ float bhi(uint u) { return __uint_as_float(u & 0xffff0000u); }
__device__ __forceinline__ uint pack2(float e, float o) {
    __hip_bfloat16 he = __float2bfloat16(e), ho = __float2bfloat16(o);
    return (uint)(*(ushort*)&he) | ((uint)(*(ushort*)&ho) << 16);
}

// ---- merged prep: x->x2t transpose | w_def->bt | w_off->bt0 | stats zero ----
// blockIdx ranges: [0,1024) x2t, [1024,3328) bt, [3328,3616) bt0, 3616 stats.
__global__ __launch_bounds__(256) void prep_all(const float* __restrict__ x,
                                                const float* __restrict__ w_def,
                                                const float* __restrict__ w_off,
                                                uint* __restrict__ x2t,
                                                ushort* __restrict__ bt,
                                                ushort* __restrict__ bt0,
                                                float* __restrict__ stats) {
    __shared__ uint tl[32][65];
    int bid = blockIdx.x;
    int t = threadIdx.x;
    if (bid < 1024) {
        // x -> bf16 position-major: x2t[(b*4096+a)*128 + cp] = {c=2cp, c=2cp+1}
        int ab  = bid & 63;
        int cpb = (bid >> 6) & 3;
        int b   = bid >> 8;
#pragma unroll
        for (int i = 0; i < 8; ++i) {
            int idx = i * 256 + t;
            int cp = idx >> 6, a = idx & 63;
            const float* p = x + ((size_t)(b * 256 + (cpb * 32 + cp) * 2)) * HW + ab * 64 + a;
            tl[cp][a] = pack2(p[0], p[HW]);
        }
        __syncthreads();
#pragma unroll
        for (int i = 0; i < 8; ++i) {
            int idx = i * 256 + t;
            int a = idx >> 5, cp = idx & 31;
            x2t[((size_t)b * 4096 + ab * 64 + a) * 128 + cpb * 32 + cp] = tl[cp][a];
        }
    } else if (bid < 3328) {
        int idx = (bid - 1024) * 256 + t;          // 589,824
        int c   = idx & 255;
        int tap = (idx >> 8) % 9;
        int o   = idx / KD;
        __hip_bfloat16 h = __float2bfloat16(w_def[(o * 256 + c) * 9 + tap]);
        bt[idx] = *(ushort*)&h;
    } else if (bid < 3616) {
        int idx = (bid - 3328) * 256 + t;          // 73,728
        int c   = idx & 255;
        int tap = (idx >> 8) % 9;
        int j   = idx / KD;
        float v = (j < 18) ? w_off[(j * 256 + c) * 9 + tap] : 0.f;
        __hip_bfloat16 h = __float2bfloat16(v);
        bt0[idx] = *(ushort*)&h;
    } else {
        float4 z = {0.f, 0.f, 0.f, 0.f};
        ((float4*)stats)[t] = z;                   // 256 float4 = 4096 B
    }
}

// ---- fused offset conv: direct implicit GEMM from x2t ----
__global__ __launch_bounds__(512) void gemm_off(const uint* __restrict__ x2t,
                                                const ushort* __restrict__ bt0,
                                                const float* __restrict__ b_off,
                                                float* __restrict__ off) {
    int id = blockIdx.x;
    int xcd = id & 7;
    int b = xcd >> 1, h = (xcd & 1) * 32 + (id >> 3);
    int t = threadIdx.x, wv = t >> 6, lane = t & 63;
    int mrow = lane & 15, quad = lane >> 4;
    int mq = wv & 3, nn = wv >> 2;

    __shared__ uint   lX[3 * 64 * 32];     // [dy][w][cp'] dwords, 24 KB
    __shared__ ushort lB[32 * 576];        // [o][72 chunks of 8, XOR-swizzled], 36 KB

    f32x4 acc = {0.f, 0.f, 0.f, 0.f};

    for (int cb = 0; cb < 4; ++cb) {
#pragma unroll
        for (int s = 0; s < 3; ++s) {      // 24 lX phases over 8 waves
            int q   = s * 8 + wv;
            int dy  = q >> 3;              // wave-uniform
            int y   = h + dy - 1;
            int sub = q & 7;
            int wl  = sub * 8 + (lane >> 3);
            int cps = ((lane & 7) ^ ((lane >> 3) & 7)) * 4;   // pre-swizzled source cp
            if ((unsigned)y < 64u) {
                const uint* src = x2t + ((size_t)(b * 4096 + y * 64 + wl)) * 128 + cb * 32 + cps;
                load_lds16(src, &lX[q * 256]);
            } else {
                uint4 z = {0u, 0u, 0u, 0u};
                *(uint4*)&lX[q * 256 + lane * 4] = z;
            }
        }
#pragma unroll
        for (int s = 0; s < 5; ++s) {      // 36 lB phases over 8 waves (guarded, wave-uniform)
            int q = s * 8 + wv;
            if (q < 36) {
                int e = q * 512 + lane * 8;
                int o  = e / 576;
                int r  = e - o * 576;
                int chp = r >> 3;
                int ch  = chp ^ (o & 7);
                int tap = ch >> 3, k8 = ch & 7;
                const ushort* src = bt0 + (size_t)o * KD + tap * 256 + cb * 64 + k8 * 8;
                load_lds16(src, &lB[q * 512]);
            }
        }
        __syncthreads();

#pragma unroll
        for (int tap = 0; tap < 9; ++tap) {
            int dy = tap / 3, dx = tap % 3;
            int xx = mq * 16 + mrow + dx - 1;
            bool vx = (unsigned)xx < 64u;
            int xc = min(max(xx, 0), 63);
#pragma unroll
            for (int kb = 0; kb < 2; ++kb) {
                int cp0 = kb * 16 + quad * 4;
                uint4 ad = {0u, 0u, 0u, 0u};
                if (vx) ad = *(const uint4*)&lX[dy * 2048 + xc * 32 + (cp0 ^ ((xc & 7) * 4))];
                bf16x8 af = *(bf16x8*)&ad;
                int o = nn * 16 + mrow;
                int chs = (tap * 8 + (((kb * 4 + quad)) ^ (o & 7)));
                bf16x8 bfr = *(const bf16x8*)&lB[o * 576 + chs * 8];
                acc = __builtin_amdgcn_mfma_f32_16x16x32_bf16(af, bfr, acc, 0, 0, 0);
            }
        }
        __syncthreads();
    }
    {
        int o = nn * 16 + mrow;
        float bias = (o < 18) ? b_off[o] : 0.f;
        f32x4 v = acc;
        v.x += bias; v.y += bias; v.z += bias; v.w += bias;
        int wpos = mq * 16 + quad * 4;
        *(f32x4*)(off + ((size_t)(b * 32 + o)) * HW + h * 64 + wpos) = v;
    }
}

// ---- fused gather + main GEMM + BN-stats ----
// P/C split, raw barriers. R7 (exposed gather latency) == R9 (hidden) == ~57 µs
// proves latency isn't the cost — the per-barrier overhead is. This round:
// 2 slices per barrier interval (36 barriers -> 18), 4 lA buffers (50 KB LDS).
// Producer: reg gathers (single gA, serial — exposure proven free), finish
// slices s+2,s+3. Consumer: 2 mfma_passes + 2 loadBs. Live-at-barrier reg set
// identical to R7 (brA/brB only) -> no spill.
__global__ __attribute__((amdgpu_waves_per_eu(4, 4))) __launch_bounds__(1024)
void fused_main(const uint* __restrict__ x2t,
                const ushort* __restrict__ bt,
                const float* __restrict__ off,
                float* __restrict__ out,
                float* __restrict__ stats) {
    int id = blockIdx.x;                      // 256 blocks
    int xcd = id & 7;
    int b = xcd >> 1, h = (xcd & 1) * 32 + (id >> 3);
    int t = threadIdx.x;
    int wv = t >> 6, lane = t & 63;
    int mrow = lane & 15, quad = lane >> 4;
    bool producer = (wv < 8);
    int ppos = (wv << 3) + (lane >> 3);       // producer position 0..63
    int pc8  = lane & 7;                      // producer 16B chunk (4 cp)
    int wvc  = wv - 8;                        // consumer wave 0..7

    __shared__ int    sAc[4][9][64];          // corner plane offsets, 9 KB
    __shared__ float  sWc[4][9][64];          // corner weights, 9 KB
    __shared__ ushort lA[4][64 * 64];         // 4 x 8 KB

    // ---- per-tile coords for all 9 taps ----
    for (int i = t; i < 576; i += 1024) {
        int tap = i >> 6, ww = i & 63;
        int hw = h * 64 + ww;
        float oy = off[((size_t)(b * 32 + 2 * tap)) * HW + hw];
        float ox = off[((size_t)(b * 32 + 2 * tap + 1)) * HW + hw];
        float py = oy + (float)(tap / 3 + h - 1);
        float px = ox + (float)(tap % 3 + ww - 1);
        float y0f = floorf(py), x0f = floorf(px);
        float wy1 = py - y0f, wx1 = px - x0f;
        float wy0 = 1.f - wy1, wx0 = 1.f - wx1;
        bool vy0 = (y0f >= 0.f) && (y0f <= 63.f);
        bool vy1 = (y0f >= -1.f) && (y0f <= 62.f);
        bool vx0 = (x0f >= 0.f) && (x0f <= 63.f);
        bool vx1 = (x0f >= -1.f) && (x0f <= 62.f);
        int iy0 = min(max((int)y0f, 0), 63),  iy1 = min(max((int)y0f + 1, 0), 63);
        int ix0 = min(max((int)x0f, 0), 63),  ix1 = min(max((int)x0f + 1, 0), 63);
        sAc[0][tap][ww] = iy0 * 64 + ix0;
        sAc[1][tap][ww] = iy0 * 64 + ix1;
        sAc[2][tap][ww] = iy1 * 64 + ix0;
        sAc[3][tap][ww] = iy1 * 64 + ix1;
        sWc[0][tap][ww] = wy0 * wx0 * (float)(vy0 && vx0);
        sWc[1][tap][ww] = wy0 * wx1 * (float)(vy0 && vx1);
        sWc[2][tap][ww] = wy1 * wx0 * (float)(vy1 && vx0);
        sWc[3][tap][ww] = wy1 * wx1 * (float)(vy1 && vx1);
    }
    __syncthreads();

    f32x4 acc[4][2];
#pragma unroll
    for (int m = 0; m < 4; ++m)
#pragma unroll
        for (int n = 0; n < 2; ++n) acc[m][n] = {0.f, 0.f, 0.f, 0.f};

    const uint* xb = x2t + (size_t)b * 4096 * 128;

    // producer: issue the 4 corner gathers for slice sl into reg set g (no wait)
    auto issue_gathers = [&](int sl, uint4 (&g)[4]) {
        int tap = sl >> 2, cb = sl & 3;
        const uint* xp = xb + cb * 32 + pc8 * 4;
        g[0] = *(const uint4*)(xp + (size_t)sAc[0][tap][ppos] * 128);
        g[1] = *(const uint4*)(xp + (size_t)sAc[1][tap][ppos] * 128);
        g[2] = *(const uint4*)(xp + (size_t)sAc[2][tap][ppos] * 128);
        g[3] = *(const uint4*)(xp + (size_t)sAc[3][tap][ppos] * 128);
    };
    // producer: interp + pack + LDS write for slice sl from reg set g
    auto finish = [&](int sl, ushort* lAb, const uint4 (&g)[4]) {
        int tap = sl >> 2;
        float f0 = sWc[0][tap][ppos], f1 = sWc[1][tap][ppos];
        float f2 = sWc[2][tap][ppos], f3 = sWc[3][tap][ppos];
        const uint* c0 = (const uint*)&g[0];
        const uint* c1 = (const uint*)&g[1];
        const uint* c2 = (const uint*)&g[2];
        const uint* c3 = (const uint*)&g[3];
        uint r[4];
#pragma unroll
        for (int j = 0; j < 4; ++j) {
            float ev = f0 * blo(c0[j]) + f1 * blo(c1[j]) + f2 * blo(c2[j]) + f3 * blo(c3[j]);
            float ov = f0 * bhi(c0[j]) + f1 * bhi(c1[j]) + f2 * bhi(c2[j]) + f3 * bhi(c3[j]);
            r[j] = pack2(ev, ov);
        }
        uint4 gg = {r[0], r[1], r[2], r[3]};
        *(uint4*)&lAb[ppos * 64 + ((pc8 ^ (ppos & 7)) * 8)] = gg;
    };
    // consumer: load this wave's B fragments for slice sl from global into regs
    auto loadB = [&](int sl, bf16x8 (&br)[4]) {
        int tap = sl >> 2, cb = sl & 3;
        const ushort* base = bt + tap * 256 + cb * 64 + quad * 8;
#pragma unroll
        for (int kb = 0; kb < 2; ++kb)
#pragma unroll
            for (int n = 0; n < 2; ++n) {
                int r = wvc * 32 + n * 16 + mrow;
                br[kb * 2 + n] = *(const bf16x8*)(base + (size_t)r * KD + kb * 32);
            }
    };
    // consumer: MFMA pass over lA buffer bi with B fragments br
    auto mfma_pass = [&](int bi, const bf16x8 (&br)[4]) {
#pragma unroll
        for (int kb = 0; kb < 2; ++kb) {
            bf16x8 af[4];
#pragma unroll
            for (int m = 0; m < 4; ++m) {
                int r = m * 16 + mrow;
                af[m] = *(const bf16x8*)&lA[bi][r * 64 + (((kb * 4 + quad) ^ (r & 7)) * 8)];
            }
#pragma unroll
            for (int n = 0; n < 2; ++n)
#pragma unroll
                for (int m = 0; m < 4; ++m)
                    acc[m][n] = __builtin_amdgcn_mfma_f32_16x16x32_bf16(af[m], br[kb * 2 + n], acc[m][n], 0, 0, 0);
        }
    };

    uint4 gA[4];
    bf16x8 brA[4], brB[4];
    // ---- prologue: slices 0,1 into lA[0],lA[1] ----
    if (producer) {
        issue_gathers(0, gA);
        finish(0, lA[0], gA);
        issue_gathers(1, gA);
        finish(1, lA[1], gA);
        asm volatile("s_waitcnt lgkmcnt(0)" ::: "memory");   // publish lA[0..1]
    } else {
        loadB(0, brA);
        loadB(1, brB);
    }
    __builtin_amdgcn_s_barrier();              // lA[0],lA[1] ready
    __builtin_amdgcn_sched_barrier(0);

    // 2 slices per barrier interval: consume lA[s&3],lA[(s+1)&3] with brA,brB;
    // produce lA[(s+2)&3],lA[(s+3)&3]. ONE barrier per 2 slices.
    for (int s = 0; s < 36; s += 2) {
        if (producer) {
            if (s + 2 < 36) {
                issue_gathers(s + 2, gA);
                finish(s + 2, lA[(s + 2) & 3], gA);
                issue_gathers(s + 3, gA);
                finish(s + 3, lA[(s + 3) & 3], gA);
                asm volatile("s_waitcnt lgkmcnt(0)" ::: "memory");   // publish
            }
        } else {
            __builtin_amdgcn_s_setprio(1);
            mfma_pass(s & 3, brA);
            mfma_pass((s + 1) & 3, brB);
            __builtin_amdgcn_s_setprio(0);
            if (s + 2 < 36) loadB(s + 2, brA);
            if (s + 3 < 36) loadB(s + 3, brB);
        }
        __builtin_amdgcn_s_barrier();
        __builtin_amdgcn_sched_barrier(0);
    }

    // ---- epilogue (consumers only): store + BN stats ----
    if (!producer) {
#pragma unroll
        for (int n = 0; n < 2; ++n) {
            int o = wvc * 32 + n * 16 + mrow;
            float ss = 0.f, qq = 0.f;
#pragma unroll
            for (int m = 0; m < 4; ++m) {
                int pos = m * 16 + quad * 4;
                f32x4 v = acc[m][n];
                *(f32x4*)(out + ((size_t)(b * 256 + o)) * HW + h * 64 + pos) = v;
                ss += v.x + v.y + v.z + v.w;
                qq += v.x * v.x + v.y * v.y + v.z * v.z + v.w * v.w;
            }
            ss += __shfl_xor(ss, 16); ss += __shfl_xor(ss, 32);
            qq += __shfl_xor(qq, 16); qq += __shfl_xor(qq, 32);
            if (quad == 0) {
                atomicAdd(&stats[o], ss);
                atomicAdd(&stats[512 + o], qq);
            }
        }
    }
}

// ---- BN finalize folded into apply: o is block-uniform ((bid>>2)&255) ----
__global__ __launch_bounds__(256) void bn_apply(float* __restrict__ out,
                                                const float* __restrict__ stats,
                                                const float* __restrict__ gamma,
                                                const float* __restrict__ beta) {
    int bid = blockIdx.x;                        // 4096
    int o = (bid >> 2) & 255;
    float S = stats[o], S2 = stats[512 + o];
    float mu  = S * (1.f / 16384.f);
    float var = S2 * (1.f / 16384.f) - mu * mu;
    float sc  = gamma[o] * rsqrtf(var + 1e-5f);
    float be  = beta[o];
    int idx4 = bid * 256 + threadIdx.x;          // 1,048,576 float4s
    float4 v = ((const float4*)out)[idx4];
    v.x = fmaxf((v.x - mu) * sc + be, 0.f);
    v.y = fmaxf((v.y - mu) * sc + be, 0.f);
    v.z = fmaxf((v.z - mu) * sc + be, 0.f);
    v.w = fmaxf((v.w - mu) * sc + be, 0.f);
    ((float4*)out)[idx4] = v;
}

extern "C" void kernel_launch(void* const* d_in, const int* in_sizes, int n_in,
                              void* d_out, int out_size, void* d_ws, size_t ws_size,
                              hipStream_t stream) {
    const float* x     = (const float*)d_in[0];
    const float* w_off = (const float*)d_in[1];
    const float* b_off = (const float*)d_in[2];
    const float* w_def = (const float*)d_in[3];
    const float* gamma = (const float*)d_in[4];
    const float* beta  = (const float*)d_in[5];
    float* out = (float*)d_out;

    char* ws = (char*)d_ws;
    uint*   x2t   = (uint*)ws;                          // 8,388,608 B
    ushort* bt    = (ushort*)(ws + 8388608);            // 1,179,648 B
    ushort* bt0   = (ushort*)(ws + 9568256);            // 147,456 B
    float*  off   = (float*)(ws + 9715712);             // 2,097,152 B
    float*  stats = (float*)(ws + 11812864);            // 4,096 B

    prep_all  <<<3617, 256, 0, stream>>>(x, w_def, w_off, x2t, bt, bt0, stats);
    gemm_off  <<<256, 512, 0, stream>>>(x2t, bt0, b_off, off);
    fused_main<<<256, 1024, 0, stream>>>(x2t, bt, off, out, stats);
    bn_apply  <<<4096, 256, 0, stream>>>(out, stats, gamma, beta);
}

// Round 11
// 144.556 us; speedup vs baseline: 1.5539x; 1.0283x over previous
//
#include <hip/hip_runtime.h>
#include <hip/hip_bf16.h>

typedef unsigned int  uint;
typedef unsigned short ushort;
typedef short bf16x8 __attribute__((ext_vector_type(8)));
typedef float f32x4  __attribute__((ext_vector_type(4)));

#define HW   4096
#define KD   2304   // 9 taps * 256 c

__device__ __forceinline__ void load_lds16(const void* g, void* l) {
    __builtin_amdgcn_global_load_lds((const __attribute__((address_space(1))) void*)g,
                                     (__attribute__((address_space(3))) void*)l, 16, 0, 0);
}
__device__ __forceinline__ float blo(uint u) { return __uint_as_float(u << 16); }
__device__ __forceinline__ float bhi(uint u) { return __uint_as_float(u & 0xffff0000u); }
__device__ __forceinline__ uint pack2(float e, float o) {
    __hip_bfloat16 he = __float2bfloat16(e), ho = __float2bfloat16(o);
    return (uint)(*(ushort*)&he) | ((uint)(*(ushort*)&ho) << 16);
}

// ---- merged prep: x->x2t transpose | w_def->bt | w_off->bt0 | stats zero ----
__global__ __launch_bounds__(256) void prep_all(const float* __restrict__ x,
                                                const float* __restrict__ w_def,
                                                const float* __restrict__ w_off,
                                                uint* __restrict__ x2t,
                                                ushort* __restrict__ bt,
                                                ushort* __restrict__ bt0,
                                                float* __restrict__ stats) {
    __shared__ uint tl[32][65];
    int bid = blockIdx.x;
    int t = threadIdx.x;
    if (bid < 1024) {
        int ab  = bid & 63;
        int cpb = (bid >> 6) & 3;
        int b   = bid >> 8;
#pragma unroll
        for (int i = 0; i < 8; ++i) {
            int idx = i * 256 + t;
            int cp = idx >> 6, a = idx & 63;
            const float* p = x + ((size_t)(b * 256 + (cpb * 32 + cp) * 2)) * HW + ab * 64 + a;
            tl[cp][a] = pack2(p[0], p[HW]);
        }
        __syncthreads();
#pragma unroll
        for (int i = 0; i < 8; ++i) {
            int idx = i * 256 + t;
            int a = idx >> 5, cp = idx & 31;
            x2t[((size_t)b * 4096 + ab * 64 + a) * 128 + cpb * 32 + cp] = tl[cp][a];
        }
    } else if (bid < 3328) {
        int idx = (bid - 1024) * 256 + t;          // 589,824
        int c   = idx & 255;
        int tap = (idx >> 8) % 9;
        int o   = idx / KD;
        __hip_bfloat16 h = __float2bfloat16(w_def[(o * 256 + c) * 9 + tap]);
        bt[idx] = *(ushort*)&h;
    } else if (bid < 3616) {
        int idx = (bid - 3328) * 256 + t;          // 73,728
        int c   = idx & 255;
        int tap = (idx >> 8) % 9;
        int j   = idx / KD;
        float v = (j < 18) ? w_off[(j * 256 + c) * 9 + tap] : 0.f;
        __hip_bfloat16 h = __float2bfloat16(v);
        bt0[idx] = *(ushort*)&h;
    } else {
        float4 z = {0.f, 0.f, 0.f, 0.f};
        ((float4*)stats)[t] = z;                   // 256 float4 = 4096 B
    }
}

// ---- MEGA kernel: offset conv (phase A) + gather/interp + main GEMM + BN stats ----
// Phase A = old gemm_off fused in: same (b,h) block mapping, result kept in LDS
// (sOff 18x64 f32) instead of a 2 MB global round-trip; staging spread over all
// 16 waves (was 8). Then coord phase reads sOff; main P/C loop = R10 verbatim.
// LDS union: phaseA {lX 24K @0, lB0 36K @24K, sOff 4.5K @60K} | main {sAc 9K @0,
// sWc 9K @9K, lA 32K @18K} — phase A buffers dead before main writes them.
__global__ __attribute__((amdgpu_waves_per_eu(4, 4))) __launch_bounds__(1024)
void fused_main(const uint* __restrict__ x2t,
                const ushort* __restrict__ bt,
                const ushort* __restrict__ bt0,
                const float* __restrict__ b_off,
                float* __restrict__ out,
                float* __restrict__ stats) {
    int id = blockIdx.x;                      // 256 blocks
    int xcd = id & 7;
    int b = xcd >> 1, h = (xcd & 1) * 32 + (id >> 3);
    int t = threadIdx.x;
    int wv = t >> 6, lane = t & 63;
    int mrow = lane & 15, quad = lane >> 4;
    bool producer = (wv < 8);
    int ppos = (wv << 3) + (lane >> 3);       // producer position 0..63
    int pc8  = lane & 7;                      // producer 16B chunk (4 cp)
    int wvc  = wv - 8;                        // consumer wave 0..7

    __shared__ __align__(16) char smem[66048];
    uint*   lX   = (uint*)smem;               // phase A: 24576 B
    ushort* lB0  = (ushort*)(smem + 24576);   // phase A: 36864 B
    float*  sOff = (float*)(smem + 61440);    // 18*64*4 = 4608 B
    int*    sAc  = (int*)smem;                // main: 4*9*64*4 = 9216 B
    float*  sWc  = (float*)(smem + 9216);     // 9216 B
    ushort* lA   = (ushort*)(smem + 18432);   // 4 * 8192 B

    // ================= phase A: offset conv (old gemm_off) =================
    {
        f32x4 accO = {0.f, 0.f, 0.f, 0.f};
        int mq = wv & 3, nn = (wv >> 2) & 1;          // valid for producer waves
        for (int cb = 0; cb < 4; ++cb) {
            // staging by ALL 16 waves (guarded, wave-uniform q)
#pragma unroll
            for (int s = 0; s < 2; ++s) {             // 24 lX phases / 16 waves
                int q = s * 16 + wv;
                if (q < 24) {
                    int dy  = q >> 3;
                    int y   = h + dy - 1;
                    int sub = q & 7;
                    int wl  = sub * 8 + (lane >> 3);
                    int cps = ((lane & 7) ^ ((lane >> 3) & 7)) * 4;
                    if ((unsigned)y < 64u) {
                        const uint* src = x2t + ((size_t)(b * 4096 + y * 64 + wl)) * 128 + cb * 32 + cps;
                        load_lds16(src, &lX[q * 256]);
                    } else {
                        uint4 z = {0u, 0u, 0u, 0u};
                        *(uint4*)&lX[q * 256 + lane * 4] = z;
                    }
                }
            }
#pragma unroll
            for (int s = 0; s < 3; ++s) {             // 36 lB0 phases / 16 waves
                int q = s * 16 + wv;
                if (q < 36) {
                    int e = q * 512 + lane * 8;
                    int o  = e / 576;
                    int r  = e - o * 576;
                    int chp = r >> 3;
                    int ch  = chp ^ (o & 7);
                    int tap = ch >> 3, k8 = ch & 7;
                    const ushort* src = bt0 + (size_t)o * KD + tap * 256 + cb * 64 + k8 * 8;
                    load_lds16(src, &lB0[q * 512]);
                }
            }
            __syncthreads();                          // drains DMA (vmcnt0)
            if (producer) {
#pragma unroll
                for (int tap = 0; tap < 9; ++tap) {
                    int dy = tap / 3, dx = tap % 3;
                    int xx = mq * 16 + mrow + dx - 1;
                    bool vx = (unsigned)xx < 64u;
                    int xc = min(max(xx, 0), 63);
#pragma unroll
                    for (int kb = 0; kb < 2; ++kb) {
                        int cp0 = kb * 16 + quad * 4;
                        uint4 ad = {0u, 0u, 0u, 0u};
                        if (vx) ad = *(const uint4*)&lX[dy * 2048 + xc * 32 + (cp0 ^ ((xc & 7) * 4))];
                        bf16x8 af = *(bf16x8*)&ad;
                        int o = nn * 16 + mrow;
                        int chs = (tap * 8 + (((kb * 4 + quad)) ^ (o & 7)));
                        bf16x8 bfr = *(const bf16x8*)&lB0[o * 576 + chs * 8];
                        accO = __builtin_amdgcn_mfma_f32_16x16x32_bf16(af, bfr, accO, 0, 0, 0);
                    }
                }
            }
            __syncthreads();
        }
        if (producer) {
            int o = nn * 16 + mrow;
            if (o < 18) {
                float bias = b_off[o];
                int wpos = mq * 16 + quad * 4;
                sOff[o * 64 + wpos + 0] = accO.x + bias;
                sOff[o * 64 + wpos + 1] = accO.y + bias;
                sOff[o * 64 + wpos + 2] = accO.z + bias;
                sOff[o * 64 + wpos + 3] = accO.w + bias;
            }
        }
        __syncthreads();                              // sOff visible to all
    }

    // ================= coord phase (reads sOff, writes sAc/sWc) =================
    for (int i = t; i < 576; i += 1024) {
        int tap = i >> 6, ww = i & 63;
        float oy = sOff[(2 * tap) * 64 + ww];
        float ox = sOff[(2 * tap + 1) * 64 + ww];
        float py = oy + (float)(tap / 3 + h - 1);
        float px = ox + (float)(tap % 3 + ww - 1);
        float y0f = floorf(py), x0f = floorf(px);
        float wy1 = py - y0f, wx1 = px - x0f;
        float wy0 = 1.f - wy1, wx0 = 1.f - wx1;
        bool vy0 = (y0f >= 0.f) && (y0f <= 63.f);
        bool vy1 = (y0f >= -1.f) && (y0f <= 62.f);
        bool vx0 = (x0f >= 0.f) && (x0f <= 63.f);
        bool vx1 = (x0f >= -1.f) && (x0f <= 62.f);
        int iy0 = min(max((int)y0f, 0), 63),  iy1 = min(max((int)y0f + 1, 0), 63);
        int ix0 = min(max((int)x0f, 0), 63),  ix1 = min(max((int)x0f + 1, 0), 63);
        sAc[0 * 576 + tap * 64 + ww] = iy0 * 64 + ix0;
        sAc[1 * 576 + tap * 64 + ww] = iy0 * 64 + ix1;
        sAc[2 * 576 + tap * 64 + ww] = iy1 * 64 + ix0;
        sAc[3 * 576 + tap * 64 + ww] = iy1 * 64 + ix1;
        sWc[0 * 576 + tap * 64 + ww] = wy0 * wx0 * (float)(vy0 && vx0);
        sWc[1 * 576 + tap * 64 + ww] = wy0 * wx1 * (float)(vy0 && vx1);
        sWc[2 * 576 + tap * 64 + ww] = wy1 * wx0 * (float)(vy1 && vx0);
        sWc[3 * 576 + tap * 64 + ww] = wy1 * wx1 * (float)(vy1 && vx1);
    }
    __syncthreads();

    // ================= main P/C loop (R10 structure verbatim) =================
    f32x4 acc[4][2];
#pragma unroll
    for (int m = 0; m < 4; ++m)
#pragma unroll
        for (int n = 0; n < 2; ++n) acc[m][n] = {0.f, 0.f, 0.f, 0.f};

    const uint* xb = x2t + (size_t)b * 4096 * 128;

    auto issue_gathers = [&](int sl, uint4 (&g)[4]) {
        int tap = sl >> 2, cb = sl & 3;
        const uint* xp = xb + cb * 32 + pc8 * 4;
        g[0] = *(const uint4*)(xp + (size_t)sAc[0 * 576 + tap * 64 + ppos] * 128);
        g[1] = *(const uint4*)(xp + (size_t)sAc[1 * 576 + tap * 64 + ppos] * 128);
        g[2] = *(const uint4*)(xp + (size_t)sAc[2 * 576 + tap * 64 + ppos] * 128);
        g[3] = *(const uint4*)(xp + (size_t)sAc[3 * 576 + tap * 64 + ppos] * 128);
    };
    auto finish = [&](int sl, ushort* lAb, const uint4 (&g)[4]) {
        int tap = sl >> 2;
        float f0 = sWc[0 * 576 + tap * 64 + ppos], f1 = sWc[1 * 576 + tap * 64 + ppos];
        float f2 = sWc[2 * 576 + tap * 64 + ppos], f3 = sWc[3 * 576 + tap * 64 + ppos];
        const uint* c0 = (const uint*)&g[0];
        const uint* c1 = (const uint*)&g[1];
        const uint* c2 = (const uint*)&g[2];
        const uint* c3 = (const uint*)&g[3];
        uint r[4];
#pragma unroll
        for (int j = 0; j < 4; ++j) {
            float ev = f0 * blo(c0[j]) + f1 * blo(c1[j]) + f2 * blo(c2[j]) + f3 * blo(c3[j]);
            float ov = f0 * bhi(c0[j]) + f1 * bhi(c1[j]) + f2 * bhi(c2[j]) + f3 * bhi(c3[j]);
            r[j] = pack2(ev, ov);
        }
        uint4 gg = {r[0], r[1], r[2], r[3]};
        *(uint4*)&lAb[ppos * 64 + ((pc8 ^ (ppos & 7)) * 8)] = gg;
    };
    auto loadB = [&](int sl, bf16x8 (&br)[4]) {
        int tap = sl >> 2, cb = sl & 3;
        const ushort* base = bt + tap * 256 + cb * 64 + quad * 8;
#pragma unroll
        for (int kb = 0; kb < 2; ++kb)
#pragma unroll
            for (int n = 0; n < 2; ++n) {
                int r = wvc * 32 + n * 16 + mrow;
                br[kb * 2 + n] = *(const bf16x8*)(base + (size_t)r * KD + kb * 32);
            }
    };
    auto mfma_pass = [&](int bi, const bf16x8 (&br)[4]) {
#pragma unroll
        for (int kb = 0; kb < 2; ++kb) {
            bf16x8 af[4];
#pragma unroll
            for (int m = 0; m < 4; ++m) {
                int r = m * 16 + mrow;
                af[m] = *(const bf16x8*)&lA[bi * 4096 + r * 64 + (((kb * 4 + quad) ^ (r & 7)) * 8)];
            }
#pragma unroll
            for (int n = 0; n < 2; ++n)
#pragma unroll
                for (int m = 0; m < 4; ++m)
                    acc[m][n] = __builtin_amdgcn_mfma_f32_16x16x32_bf16(af[m], br[kb * 2 + n], acc[m][n], 0, 0, 0);
        }
    };

    uint4 gA[4];
    bf16x8 brA[4], brB[4];
    if (producer) {
        issue_gathers(0, gA);
        finish(0, &lA[0], gA);
        issue_gathers(1, gA);
        finish(1, &lA[4096], gA);
        asm volatile("s_waitcnt lgkmcnt(0)" ::: "memory");   // publish lA[0..1]
    } else {
        loadB(0, brA);
        loadB(1, brB);
    }
    __builtin_amdgcn_s_barrier();
    __builtin_amdgcn_sched_barrier(0);

    for (int s = 0; s < 36; s += 2) {
        if (producer) {
            if (s + 2 < 36) {
                issue_gathers(s + 2, gA);
                finish(s + 2, &lA[((s + 2) & 3) * 4096], gA);
                issue_gathers(s + 3, gA);
                finish(s + 3, &lA[((s + 3) & 3) * 4096], gA);
                asm volatile("s_waitcnt lgkmcnt(0)" ::: "memory");
            }
        } else {
            __builtin_amdgcn_s_setprio(1);
            mfma_pass(s & 3, brA);
            mfma_pass((s + 1) & 3, brB);
            __builtin_amdgcn_s_setprio(0);
            if (s + 2 < 36) loadB(s + 2, brA);
            if (s + 3 < 36) loadB(s + 3, brB);
        }
        __builtin_amdgcn_s_barrier();
        __builtin_amdgcn_sched_barrier(0);
    }

    // ---- epilogue (consumers only): store + BN stats ----
    if (!producer) {
#pragma unroll
        for (int n = 0; n < 2; ++n) {
            int o = wvc * 32 + n * 16 + mrow;
            float ss = 0.f, qq = 0.f;
#pragma unroll
            for (int m = 0; m < 4; ++m) {
                int pos = m * 16 + quad * 4;
                f32x4 v = acc[m][n];
                *(f32x4*)(out + ((size_t)(b * 256 + o)) * HW + h * 64 + pos) = v;
                ss += v.x + v.y + v.z + v.w;
                qq += v.x * v.x + v.y * v.y + v.z * v.z + v.w * v.w;
            }
            ss += __shfl_xor(ss, 16); ss += __shfl_xor(ss, 32);
            qq += __shfl_xor(qq, 16); qq += __shfl_xor(qq, 32);
            if (quad == 0) {
                atomicAdd(&stats[o], ss);
                atomicAdd(&stats[512 + o], qq);
            }
        }
    }
}

// ---- BN finalize folded into apply: o is block-uniform ((bid>>2)&255) ----
__global__ __launch_bounds__(256) void bn_apply(float* __restrict__ out,
                                                const float* __restrict__ stats,
                                                const float* __restrict__ gamma,
                                                const float* __restrict__ beta) {
    int bid = blockIdx.x;                        // 4096
    int o = (bid >> 2) & 255;
    float S = stats[o], S2 = stats[512 + o];
    float mu  = S * (1.f / 16384.f);
    float var = S2 * (1.f / 16384.f) - mu * mu;
    float sc  = gamma[o] * rsqrtf(var + 1e-5f);
    float be  = beta[o];
    int idx4 = bid * 256 + threadIdx.x;          // 1,048,576 float4s
    float4 v = ((const float4*)out)[idx4];
    v.x = fmaxf((v.x - mu) * sc + be, 0.f);
    v.y = fmaxf((v.y - mu) * sc + be, 0.f);
    v.z = fmaxf((v.z - mu) * sc + be, 0.f);
    v.w = fmaxf((v.w - mu) * sc + be, 0.f);
    ((float4*)out)[idx4] = v;
}

extern "C" void kernel_launch(void* const* d_in, const int* in_sizes, int n_in,
                              void* d_out, int out_size, void* d_ws, size_t ws_size,
                              hipStream_t stream) {
    const float* x     = (const float*)d_in[0];
    const float* w_off = (const float*)d_in[1];
    const float* b_off = (const float*)d_in[2];
    const float* w_def = (const float*)d_in[3];
    const float* gamma = (const float*)d_in[4];
    const float* beta  = (const float*)d_in[5];
    float* out = (float*)d_out;

    char* ws = (char*)d_ws;
    uint*   x2t   = (uint*)ws;                          // 8,388,608 B
    ushort* bt    = (ushort*)(ws + 8388608);            // 1,179,648 B
    ushort* bt0   = (ushort*)(ws + 9568256);            // 147,456 B
    float*  stats = (float*)(ws + 9715712);             // 4,096 B

    prep_all  <<<3617, 256, 0, stream>>>(x, w_def, w_off, x2t, bt, bt0, stats);
    fused_main<<<256, 1024, 0, stream>>>(x2t, bt, bt0, b_off, out, stats);
    bn_apply  <<<4096, 256, 0, stream>>>(out, stats, gamma, beta);
}